// Round 16
// baseline (1628.965 us; speedup 1.0000x reference)
//
#include <hip/hip_runtime.h>

#define TT 1500
#define BB 96
#define VV 128
#define LGT 256
#define LCAP 512
#define NEGF (-1.0e30f)
#define L2E 1.4426950408889634f
#define LN2F 0.6931471805599453f
#define NW 11  // waves per CTC block (704 threads)

// ---------------------------------------------------------------------------
// Kernel 1: greedy decode (unchanged).
// ---------------------------------------------------------------------------
__global__ __launch_bounds__(256) void decode_kernel(
    const float* __restrict__ acts, const int* __restrict__ act_lens,
    int* __restrict__ dec, int* __restrict__ dec_lens) {
  __shared__ int preds[TT];
  __shared__ int sc[256];
  const int b = blockIdx.x;
  const int tid = threadIdx.x;
  const int Tl = act_lens[b];
  for (int t = tid; t < Tl; t += 256) {
    const float4* r4 = (const float4*)(acts + ((size_t)t * BB + b) * VV);
    float best = -3.4e38f;
    int bi = 0;
#pragma unroll
    for (int i = 0; i < VV / 4; i++) {
      float4 v = r4[i];
      if (v.x > best) { best = v.x; bi = 4 * i; }
      if (v.y > best) { best = v.y; bi = 4 * i + 1; }
      if (v.z > best) { best = v.z; bi = 4 * i + 2; }
      if (v.w > best) { best = v.w; bi = 4 * i + 3; }
    }
    preds[t] = bi;
  }
  __syncthreads();

  int pv[6];
  bool fl[6];
  int cnt = 0;
#pragma unroll
  for (int j = 0; j < 6; j++) {
    int t = tid * 6 + j;
    bool valid = t < Tl;
    int p = valid ? preds[t] : 0;
    int pr = (t == 0) ? -1 : (valid ? preds[t - 1] : -1);
    bool f = valid && (p != 0) && (p != pr);
    pv[j] = p;
    fl[j] = f;
    cnt += f;
  }
  sc[tid] = cnt;
  __syncthreads();
  for (int off = 1; off < 256; off <<= 1) {
    int v = sc[tid];
    if (tid >= off) v += sc[tid - off];
    __syncthreads();
    sc[tid] = v;
    __syncthreads();
  }
  int pos = sc[tid] - cnt;  // exclusive prefix
  int total = sc[255];
  int* db = dec + (size_t)b * LCAP;
#pragma unroll
  for (int j = 0; j < 6; j++) {
    if (fl[j]) {
      if (pos < LCAP) db[pos] = pv[j];
      pos++;
    }
  }
  if (tid == 0) {
    if (total == 0) db[0] = 0;
    dec_lens[b] = max(1, min(total, LCAP));
  }
}

// ---------------------------------------------------------------------------
// Kernel 2: CTC (r15 structure, absmax 0.0), templated diagnostic MODE:
//   0 = real (feeds d_out)  1 = dep-broken (same mix, no cross-step chain)
//   2 = no-vmem (in-loop PREF deleted; feedback intact)
// ---------------------------------------------------------------------------
__device__ __forceinline__ float shr1_negf(float x) {
  int r = __builtin_amdgcn_update_dpp(__float_as_int(NEGF), __float_as_int(x),
                                      0x138, 0xf, 0xf, false);
  return __int_as_float(r);
}

template <int MODE>
__global__ __launch_bounds__(64 * NW, 1) void ctc_t(
    const float* __restrict__ acts, const int* __restrict__ labels_gt,
    const int* __restrict__ act_lens, const int* __restrict__ label_lens,
    const int* __restrict__ dec, const int* __restrict__ dec_lens,
    float* __restrict__ ends, float* __restrict__ wsink) {
  __shared__ float xall[2 * LCAP + 2];
  __shared__ float fin[2];
  const int b = blockIdx.x >> 1;
  const int hyp = blockIdx.x & 1;
  const int Tl = act_lens[b];
  const int len = hyp ? dec_lens[b] : label_lens[b];
  const int* lab = hyp ? (dec + (size_t)b * LCAP) : (labels_gt + (size_t)b * LGT);
  const int S = 2 * len + 1;
  const float* act_b = acts + (size_t)b * VV;
  const int Tlm1 = Tl - 1;

  const int tid = threadIdx.x;
  const int lane = tid & 63, wv = tid >> 6;
  const int oS = 2 * ((S + 2 * NW - 1) / (2 * NW));
  const int Se = (S + 1) & ~1;
  const int o0 = min(wv * oS, Se);
  const int o1 = min(o0 + oS, S);
  const int p0 = max(0, o0 - 26);
  const int s0 = p0 + 2 * lane;
  const int s1 = s0 + 1;

  int e1 = 0;
  bool skip = false;
  if (s1 < S) {
    int li = s1 >> 1;
    e1 = lab[li];
    if (s1 >= 3) skip = (e1 != 0) && (e1 != lab[li - 1]);
  }

  float a0 = NEGF, a1 = NEGF;
  if (wv == 0 && lane == 0) {
    a0 = act_b[0] * L2E;
    a1 = act_b[e1] * L2E;
  }
  float acc0 = 0.f, acc1 = 0.f;  // MODE 1 sinks

  float gL0, gL1, gL2, gL3, gL4, gL5;
  float gB0, gB1, gB2, gB3, gB4, gB5;

#define PREF0(GL, GB, ROW)                                 \
  {                                                        \
    const float* rp_ = act_b + (size_t)(ROW) * (BB * VV);  \
    GB = rp_[0];                                           \
    GL = rp_[e1];                                          \
  }

#define PREF(GL, GB, ROW)                                  \
  if constexpr (MODE != 2) {                               \
    const float* rp_ = act_b + (size_t)(ROW) * (BB * VV);  \
    GB = rp_[0];                                           \
    GL = rp_[e1];                                          \
  }

#define STEPK(GL, GB)                                                     \
  {                                                                       \
    float A0_, A1_;                                                       \
    if constexpr (MODE == 1) {                                            \
      A0_ = __builtin_fmaf(GB, 1e-30f, a0);                               \
      A1_ = __builtin_fmaf(GL, 1e-30f, a1);                               \
    } else {                                                              \
      A0_ = a0;                                                           \
      A1_ = a1;                                                           \
    }                                                                     \
    float pe = shr1_negf(A1_);                                            \
    float m0 = fmaxf(A0_, pe);                                            \
    float d0 = fminf(A0_, pe) - m0;                                       \
    float n0 = m0 + __builtin_log2f(1.0f + __builtin_exp2f(d0));          \
    float c2 = skip ? pe : NEGF;                                          \
    float m1 = fmaxf(fmaxf(A1_, A0_), c2);                                \
    float dm = __builtin_amdgcn_fmed3f(A1_, A0_, c2) - m1;                \
    float dn = fminf(fminf(A1_, A0_), c2) - m1;                           \
    float n1 = m1 + __builtin_log2f(1.0f + __builtin_exp2f(dm) +          \
                                    __builtin_exp2f(dn));                 \
    if constexpr (MODE == 1) {                                            \
      acc0 += __builtin_fmaf(GB, L2E, n0);                                \
      acc1 += __builtin_fmaf(GL, L2E, n1);                                \
    } else {                                                              \
      a0 = __builtin_fmaf(GB, L2E, n0);                                   \
      a1 = __builtin_fmaf(GL, L2E, n1);                                   \
    }                                                                     \
  }

#define REFRESH()                                        \
  {                                                      \
    asm volatile("s_waitcnt lgkmcnt(0)" ::: "memory");   \
    __builtin_amdgcn_s_barrier();                        \
    if (s0 >= o0 && s0 < o1) xall[s0] = a0;              \
    if (s1 >= o0 && s1 < o1) xall[s1] = a1;              \
    asm volatile("s_waitcnt lgkmcnt(0)" ::: "memory");   \
    __builtin_amdgcn_s_barrier();                        \
    if (s0 < o0) {                                       \
      a0 = xall[s0];                                     \
      a1 = (s1 < S) ? xall[s1] : NEGF;                   \
    }                                                    \
  }

#define W1(OFF, GL, GB)                    \
  STEPK(GL, GB);                           \
  PREF(GL, GB, min(t + (OFF) + 6, Tlm1));

#define T1(GL, GB)                         \
  STEPK(GL, GB);                           \
  PREF(GL, GB, min(t + 6, Tlm1));          \
  ++t;                                     \
  if (t >= Tl) break;

  PREF0(gL0, gB0, min(1, Tlm1));
  PREF0(gL1, gB1, min(2, Tlm1));
  PREF0(gL2, gB2, min(3, Tlm1));
  PREF0(gL3, gB3, min(4, Tlm1));
  PREF0(gL4, gB4, min(5, Tlm1));
  PREF0(gL5, gB5, min(6, Tlm1));

  int t = 1;
  while (t + 12 <= Tl) {
    W1(0, gL0, gB0)
    W1(1, gL1, gB1)
    W1(2, gL2, gB2)
    W1(3, gL3, gB3)
    W1(4, gL4, gB4)
    W1(5, gL5, gB5)
    W1(6, gL0, gB0)
    W1(7, gL1, gB1)
    W1(8, gL2, gB2)
    W1(9, gL3, gB3)
    W1(10, gL4, gB4)
    W1(11, gL5, gB5)
    t += 12;
    REFRESH();
  }
  while (t < Tl) {
    T1(gL0, gB0)
    T1(gL1, gB1)
    T1(gL2, gB2)
    T1(gL3, gB3)
    T1(gL4, gB4)
    T1(gL5, gB5)
  }
#undef T1
#undef W1
#undef REFRESH
#undef STEPK
#undef PREF
#undef PREF0

  if constexpr (MODE == 1) {
    if (lane == 0) wsink[blockIdx.x * NW + wv] = acc0 + acc1;  // live sink
    return;
  }
  __syncthreads();
  if (s0 >= o0 && s0 < o1 && s0 == 2 * len) fin[0] = a0;
  if (s1 >= o0 && s1 < o1 && s1 == 2 * len - 1) fin[1] = a1;
  __syncthreads();
  if (tid == 0) {
    float a = fin[0], c = fin[1];
    float m = fmaxf(a, c);
    float e = m + __builtin_log2f(__builtin_exp2f(a - m) + __builtin_exp2f(c - m));
    ends[hyp * BB + b] = e;
  }
}

// ---------------------------------------------------------------------------
// P3: clock calibration — 65536-deep dependent FMA chain (~4 cy each).
// Expected dur: ~109 us @2.4 GHz; ~187 us @1.4 GHz. Same grid/LDS shape.
// ---------------------------------------------------------------------------
__global__ __launch_bounds__(64 * NW, 1) void clock_probe(float* sink) {
  float a = (float)(threadIdx.x + blockIdx.x) * 1e-6f;
#pragma unroll 32
  for (int i = 0; i < 65536; i++) a = __builtin_fmaf(a, 1.0000001f, 0.5f);
  if ((threadIdx.x & 63) == 0)
    sink[blockIdx.x * NW + (threadIdx.x >> 6)] = a;
}

// ---------------------------------------------------------------------------
// Kernel 3: out[b] = (end_hyp' - end_gt') * ln2 + 1.0
// ---------------------------------------------------------------------------
__global__ void final_kernel(const float* __restrict__ ends,
                             float* __restrict__ out) {
  int b = threadIdx.x;
  if (b < BB) out[b] = (ends[BB + b] - ends[b]) * LN2F + 1.0f;
}

extern "C" void kernel_launch(void* const* d_in, const int* in_sizes, int n_in,
                              void* d_out, int out_size, void* d_ws,
                              size_t ws_size, hipStream_t stream) {
  const float* acts = (const float*)d_in[0];
  const int* labels = (const int*)d_in[1];
  const int* act_lens = (const int*)d_in[2];
  const int* label_lens = (const int*)d_in[3];
  float* out = (float*)d_out;

  char* ws = (char*)d_ws;
  int* dec = (int*)ws;                                 // B*LCAP ints
  size_t off = (size_t)BB * LCAP * 4;
  int* dec_lens = (int*)(ws + off);                    // B ints
  off += BB * 4;
  float* ends = (float*)(ws + off);                    // 2*B floats (real)
  off += 2 * BB * 4;
  float* endsP2 = (float*)(ws + off);                  // 2*B floats (P2 sink)
  off += 2 * BB * 4;
  float* sinkP1 = (float*)(ws + off);                  // 2*B*NW floats
  off += 2 * BB * NW * 4;
  float* sinkP3 = (float*)(ws + off);                  // 2*B*NW floats

  decode_kernel<<<dim3(BB), dim3(256), 0, stream>>>(acts, act_lens, dec, dec_lens);
  // Real kernel (r15-identical config): 84KB dynamic LDS -> 1 block/CU.
  ctc_t<0><<<dim3(2 * BB), dim3(64 * NW), 84 * 1024, stream>>>(
      acts, labels, act_lens, label_lens, dec, dec_lens, ends, sinkP1);
  final_kernel<<<dim3(1), dim3(128), 0, stream>>>(ends, out);
  // --- diagnostics (sacrificial timing this round) ---
  ctc_t<1><<<dim3(2 * BB), dim3(64 * NW), 84 * 1024, stream>>>(
      acts, labels, act_lens, label_lens, dec, dec_lens, endsP2, sinkP1);
  ctc_t<2><<<dim3(2 * BB), dim3(64 * NW), 84 * 1024, stream>>>(
      acts, labels, act_lens, label_lens, dec, dec_lens, endsP2, sinkP1);
  clock_probe<<<dim3(2 * BB), dim3(64 * NW), 84 * 1024, stream>>>(sinkP3);
}

// Round 17
// 460.622 us; speedup vs baseline: 3.5364x; 3.5364x over previous
//
#include <hip/hip_runtime.h>

#define TT 1500
#define BB 96
#define VV 128
#define LGT 256
#define LCAP 512
#define NEGF (-1.0e30f)
#define L2E 1.4426950408889634f
#define LN2F 0.6931471805599453f
#define NW 11  // waves per CTC block (704 threads)
#define GH 26  // ghost states (covers 12-step window: 24 < 26)

// ---------------------------------------------------------------------------
// Kernel 1: greedy decode (unchanged).
// ---------------------------------------------------------------------------
__global__ __launch_bounds__(256) void decode_kernel(
    const float* __restrict__ acts, const int* __restrict__ act_lens,
    int* __restrict__ dec, int* __restrict__ dec_lens) {
  __shared__ int preds[TT];
  __shared__ int sc[256];
  const int b = blockIdx.x;
  const int tid = threadIdx.x;
  const int Tl = act_lens[b];
  for (int t = tid; t < Tl; t += 256) {
    const float4* r4 = (const float4*)(acts + ((size_t)t * BB + b) * VV);
    float best = -3.4e38f;
    int bi = 0;
#pragma unroll
    for (int i = 0; i < VV / 4; i++) {
      float4 v = r4[i];
      if (v.x > best) { best = v.x; bi = 4 * i; }
      if (v.y > best) { best = v.y; bi = 4 * i + 1; }
      if (v.z > best) { best = v.z; bi = 4 * i + 2; }
      if (v.w > best) { best = v.w; bi = 4 * i + 3; }
    }
    preds[t] = bi;
  }
  __syncthreads();

  int pv[6];
  bool fl[6];
  int cnt = 0;
#pragma unroll
  for (int j = 0; j < 6; j++) {
    int t = tid * 6 + j;
    bool valid = t < Tl;
    int p = valid ? preds[t] : 0;
    int pr = (t == 0) ? -1 : (valid ? preds[t - 1] : -1);
    bool f = valid && (p != 0) && (p != pr);
    pv[j] = p;
    fl[j] = f;
    cnt += f;
  }
  sc[tid] = cnt;
  __syncthreads();
  for (int off = 1; off < 256; off <<= 1) {
    int v = sc[tid];
    if (tid >= off) v += sc[tid - off];
    __syncthreads();
    sc[tid] = v;
    __syncthreads();
  }
  int pos = sc[tid] - cnt;  // exclusive prefix
  int total = sc[255];
  int* db = dec + (size_t)b * LCAP;
#pragma unroll
  for (int j = 0; j < 6; j++) {
    if (fl[j]) {
      if (pos < LCAP) db[pos] = pv[j];
      pos++;
    }
  }
  if (tid == 0) {
    if (total == 0) db[0] = 0;
    dec_lens[b] = max(1, min(total, LCAP));
  }
}

// ---------------------------------------------------------------------------
// Kernel 2: CTC (r15 math/layout, absmax 0.0). CHANGE vs r15: the per-window
// block-wide REFRESH barrier is replaced by PAIRWISE producer/consumer flag
// sync (LDS atomics, acquire/release, double-buffered slots, 2-window
// backpressure). Ghost data flows strictly downward (wave w reads only waves
// [w-ceil(GH/oS), w)), so no s_barrier is needed in the main loop; waves
// drift and self-synchronize locally. Exchange values are tied to the same
// step index k -> math identical to r15's REFRESH.
// ---------------------------------------------------------------------------
__device__ __forceinline__ float shr1_negf(float x) {
  int r = __builtin_amdgcn_update_dpp(__float_as_int(NEGF), __float_as_int(x),
                                      0x138, 0xf, 0xf, false);
  return __int_as_float(r);
}

__global__ __launch_bounds__(64 * NW, 1) void ctc_kernel(
    const float* __restrict__ acts, const int* __restrict__ labels_gt,
    const int* __restrict__ act_lens, const int* __restrict__ label_lens,
    const int* __restrict__ dec, const int* __restrict__ dec_lens,
    float* __restrict__ ends) {
  __shared__ float xp[2][2 * LCAP + 2];  // parity-slotted exchange buffer
  __shared__ int prodf[NW], consf[NW];
  __shared__ float fin[2];
  const int b = blockIdx.x >> 1;
  const int hyp = blockIdx.x & 1;
  const int Tl = act_lens[b];
  const int len = hyp ? dec_lens[b] : label_lens[b];
  const int* lab = hyp ? (dec + (size_t)b * LCAP) : (labels_gt + (size_t)b * LGT);
  const int S = 2 * len + 1;
  const float* act_b = acts + (size_t)b * VV;
  const int Tlm1 = Tl - 1;

  const int tid = threadIdx.x;
  const int lane = tid & 63, wv = tid >> 6;
  const int oS = 2 * ((S + 2 * NW - 1) / (2 * NW));  // even owned span
  const int Se = (S + 1) & ~1;
  const int o0 = min(wv * oS, Se);
  const int o1 = min(o0 + oS, S);
  const int p0 = max(0, o0 - GH);
  const int s0 = p0 + 2 * lane;  // blank (even)
  const int s1 = s0 + 1;         // label (odd)
  const int ceilc = (GH + oS - 1) / oS;
  const int wlo = max(0, wv - ceilc);
  const int whi = min(NW - 1, wv + ceilc);

  if (tid < NW) {
    prodf[tid] = 0;
    consf[tid] = 0;
  }
  __syncthreads();

  int e1 = 0;
  bool skip = false;
  if (s1 < S) {
    int li = s1 >> 1;
    e1 = lab[li];
    if (s1 >= 3) skip = (e1 != 0) && (e1 != lab[li - 1]);
  }

  float a0 = NEGF, a1 = NEGF;
  if (wv == 0 && lane == 0) {
    a0 = act_b[0] * L2E;
    a1 = act_b[e1] * L2E;
  }

  float gL0, gL1, gL2, gL3, gL4, gL5;
  float gB0, gB1, gB2, gB3, gB4, gB5;

#define PREF(GL, GB, ROW)                                  \
  {                                                        \
    const float* rp_ = act_b + (size_t)(ROW) * (BB * VV);  \
    GB = rp_[0];                                           \
    GL = rp_[e1];                                          \
  }

#define STEPK(GL, GB)                                                     \
  {                                                                       \
    float pe = shr1_negf(a1);                                             \
    float m0 = fmaxf(a0, pe);                                             \
    float d0 = fminf(a0, pe) - m0;                                        \
    float n0 = m0 + __builtin_log2f(1.0f + __builtin_exp2f(d0));          \
    float c2 = skip ? pe : NEGF;                                          \
    float m1 = fmaxf(fmaxf(a1, a0), c2);                                  \
    float dm = __builtin_amdgcn_fmed3f(a1, a0, c2) - m1;                  \
    float dn = fminf(fminf(a1, a0), c2) - m1;                             \
    float n1 = m1 + __builtin_log2f(1.0f + __builtin_exp2f(dm) +          \
                                    __builtin_exp2f(dn));                 \
    a0 = __builtin_fmaf(GB, L2E, n0);                                     \
    a1 = __builtin_fmaf(GL, L2E, n1);                                     \
  }

  // pairwise flag-synced exchange (replaces block-wide REFRESH)
#define EXCHANGE(K)                                                         \
  {                                                                         \
    if (wv < NW - 1) { /* backpressure: my readers consumed slot K-2 */     \
      for (int w2 = wv + 1; w2 <= whi; ++w2)                                \
        while (__hip_atomic_load(&consf[w2], __ATOMIC_ACQUIRE,              \
                                 __HIP_MEMORY_SCOPE_WORKGROUP) < (K)-2) {}  \
    }                                                                       \
    float* xs = xp[(K)&1];                                                  \
    if (s0 >= o0 && s0 < o1) xs[s0] = a0;                                   \
    if (s1 >= o0 && s1 < o1) xs[s1] = a1;                                   \
    asm volatile("s_waitcnt lgkmcnt(0)" ::: "memory");                      \
    if (wv < NW - 1 && lane == 0)                                           \
      __hip_atomic_store(&prodf[wv], (K), __ATOMIC_RELEASE,                 \
                         __HIP_MEMORY_SCOPE_WORKGROUP);                     \
    if (wv > 0) {                                                           \
      for (int w2 = wlo; w2 < wv; ++w2)                                     \
        while (__hip_atomic_load(&prodf[w2], __ATOMIC_ACQUIRE,              \
                                 __HIP_MEMORY_SCOPE_WORKGROUP) < (K)) {}    \
      if (s0 < o0) {                                                        \
        a0 = xs[s0];                                                        \
        a1 = (s1 < S) ? xs[s1] : NEGF;                                      \
      }                                                                     \
      asm volatile("s_waitcnt lgkmcnt(0)" ::: "memory");                    \
      if (lane == 0)                                                        \
        __hip_atomic_store(&consf[wv], (K), __ATOMIC_RELEASE,               \
                           __HIP_MEMORY_SCOPE_WORKGROUP);                   \
    }                                                                       \
  }

#define W1(OFF, GL, GB)                    \
  STEPK(GL, GB);                           \
  PREF(GL, GB, min(t + (OFF) + 6, Tlm1));

#define T1(GL, GB)                         \
  STEPK(GL, GB);                           \
  PREF(GL, GB, min(t + 6, Tlm1));          \
  ++t;                                     \
  if (t >= Tl) break;

  PREF(gL0, gB0, min(1, Tlm1));
  PREF(gL1, gB1, min(2, Tlm1));
  PREF(gL2, gB2, min(3, Tlm1));
  PREF(gL3, gB3, min(4, Tlm1));
  PREF(gL4, gB4, min(5, Tlm1));
  PREF(gL5, gB5, min(6, Tlm1));

  int t = 1, k = 0;
  while (t + 12 <= Tl) {
    W1(0, gL0, gB0)
    W1(1, gL1, gB1)
    W1(2, gL2, gB2)
    W1(3, gL3, gB3)
    W1(4, gL4, gB4)
    W1(5, gL5, gB5)
    W1(6, gL0, gB0)
    W1(7, gL1, gB1)
    W1(8, gL2, gB2)
    W1(9, gL3, gB3)
    W1(10, gL4, gB4)
    W1(11, gL5, gB5)
    t += 12;
    ++k;
    EXCHANGE(k);
  }
  while (t < Tl) {
    T1(gL0, gB0)
    T1(gL1, gB1)
    T1(gL2, gB2)
    T1(gL3, gB3)
    T1(gL4, gB4)
    T1(gL5, gB5)
  }
#undef T1
#undef W1
#undef EXCHANGE
#undef STEPK
#undef PREF

  // final: block barrier joins the (bounded) wave skew, then reduce
  __syncthreads();
  if (s0 >= o0 && s0 < o1 && s0 == 2 * len) fin[0] = a0;
  if (s1 >= o0 && s1 < o1 && s1 == 2 * len - 1) fin[1] = a1;
  __syncthreads();
  if (tid == 0) {
    float a = fin[0], c = fin[1];
    float m = fmaxf(a, c);
    float e = m + __builtin_log2f(__builtin_exp2f(a - m) + __builtin_exp2f(c - m));
    ends[hyp * BB + b] = e;
  }
}

// ---------------------------------------------------------------------------
// Kernel 3: out[b] = (end_hyp' - end_gt') * ln2 + 1.0  (log2-domain ends)
// ---------------------------------------------------------------------------
__global__ void final_kernel(const float* __restrict__ ends,
                             float* __restrict__ out) {
  int b = threadIdx.x;
  if (b < BB) out[b] = (ends[BB + b] - ends[b]) * LN2F + 1.0f;
}

extern "C" void kernel_launch(void* const* d_in, const int* in_sizes, int n_in,
                              void* d_out, int out_size, void* d_ws,
                              size_t ws_size, hipStream_t stream) {
  const float* acts = (const float*)d_in[0];
  const int* labels = (const int*)d_in[1];
  const int* act_lens = (const int*)d_in[2];
  const int* label_lens = (const int*)d_in[3];
  float* out = (float*)d_out;

  char* ws = (char*)d_ws;
  int* dec = (int*)ws;                                          // B*LCAP ints
  int* dec_lens = (int*)(ws + (size_t)BB * LCAP * 4);           // B ints
  float* ends = (float*)(ws + (size_t)BB * LCAP * 4 + BB * 4);  // 2*B floats

  decode_kernel<<<dim3(BB), dim3(256), 0, stream>>>(acts, act_lens, dec, dec_lens);
  // 84KB dynamic LDS (as in r15) to keep 1 block/CU; grid 192 <= 256 CUs.
  ctc_kernel<<<dim3(2 * BB), dim3(64 * NW), 84 * 1024, stream>>>(
      acts, labels, act_lens, label_lens, dec, dec_lens, ends);
  final_kernel<<<dim3(1), dim3(128), 0, stream>>>(ends, out);
}

// Round 18
// 394.842 us; speedup vs baseline: 4.1256x; 1.1666x over previous
//
#include <hip/hip_runtime.h>

#define TT 1500
#define BB 96
#define VV 128
#define LGT 256
#define LCAP 512
#define NEGF (-1.0e30f)
#define L2E 1.4426950408889634f
#define LN2F 0.6931471805599453f
#define NW 11  // waves per CTC block (704 threads)

// ---------------------------------------------------------------------------
// Kernel 1: greedy decode (unchanged).
// ---------------------------------------------------------------------------
__global__ __launch_bounds__(256) void decode_kernel(
    const float* __restrict__ acts, const int* __restrict__ act_lens,
    int* __restrict__ dec, int* __restrict__ dec_lens) {
  __shared__ int preds[TT];
  __shared__ int sc[256];
  const int b = blockIdx.x;
  const int tid = threadIdx.x;
  const int Tl = act_lens[b];
  for (int t = tid; t < Tl; t += 256) {
    const float4* r4 = (const float4*)(acts + ((size_t)t * BB + b) * VV);
    float best = -3.4e38f;
    int bi = 0;
#pragma unroll
    for (int i = 0; i < VV / 4; i++) {
      float4 v = r4[i];
      if (v.x > best) { best = v.x; bi = 4 * i; }
      if (v.y > best) { best = v.y; bi = 4 * i + 1; }
      if (v.z > best) { best = v.z; bi = 4 * i + 2; }
      if (v.w > best) { best = v.w; bi = 4 * i + 3; }
    }
    preds[t] = bi;
  }
  __syncthreads();

  int pv[6];
  bool fl[6];
  int cnt = 0;
#pragma unroll
  for (int j = 0; j < 6; j++) {
    int t = tid * 6 + j;
    bool valid = t < Tl;
    int p = valid ? preds[t] : 0;
    int pr = (t == 0) ? -1 : (valid ? preds[t - 1] : -1);
    bool f = valid && (p != 0) && (p != pr);
    pv[j] = p;
    fl[j] = f;
    cnt += f;
  }
  sc[tid] = cnt;
  __syncthreads();
  for (int off = 1; off < 256; off <<= 1) {
    int v = sc[tid];
    if (tid >= off) v += sc[tid - off];
    __syncthreads();
    sc[tid] = v;
    __syncthreads();
  }
  int pos = sc[tid] - cnt;  // exclusive prefix
  int total = sc[255];
  int* db = dec + (size_t)b * LCAP;
#pragma unroll
  for (int j = 0; j < 6; j++) {
    if (fl[j]) {
      if (pos < LCAP) db[pos] = pv[j];
      pos++;
    }
  }
  if (tid == 0) {
    if (total == 0) db[0] = 0;
    dec_lens[b] = max(1, min(total, LCAP));
  }
}

// ---------------------------------------------------------------------------
// Kernel 2: CTC, r15 structure exactly (434us, absmax 0.0). SINGLE CHANGE:
// STEPK uses lse associativity — lse3(a1,a0,pe) = lse2(a1, lse2(a0,pe)) —
// and lse2(a0,pe) is already the blank state's sum u. So both states cost
// one lse2 each: 4 trans + 15 VALU per step (was 5 trans + 22 VALU).
// w = skip ? u : a0 selects the label state's second operand.
// ---------------------------------------------------------------------------
__device__ __forceinline__ float shr1_negf(float x) {
  // lane i <- lane i-1's x; lane 0 <- NEGF.  DPP ctrl 0x138 = wave_shr:1.
  int r = __builtin_amdgcn_update_dpp(__float_as_int(NEGF), __float_as_int(x),
                                      0x138, 0xf, 0xf, false);
  return __int_as_float(r);
}

__global__ __launch_bounds__(64 * NW, 1) void ctc_kernel(
    const float* __restrict__ acts, const int* __restrict__ labels_gt,
    const int* __restrict__ act_lens, const int* __restrict__ label_lens,
    const int* __restrict__ dec, const int* __restrict__ dec_lens,
    float* __restrict__ ends) {
  __shared__ float xall[2 * LCAP + 2];
  __shared__ float fin[2];
  const int b = blockIdx.x >> 1;
  const int hyp = blockIdx.x & 1;
  const int Tl = act_lens[b];
  const int len = hyp ? dec_lens[b] : label_lens[b];
  const int* lab = hyp ? (dec + (size_t)b * LCAP) : (labels_gt + (size_t)b * LGT);
  const int S = 2 * len + 1;
  const float* act_b = acts + (size_t)b * VV;  // acts[(t*BB + b)*VV + v]
  const int Tlm1 = Tl - 1;

  const int tid = threadIdx.x;
  const int lane = tid & 63, wv = tid >> 6;
  const int oS = 2 * ((S + 2 * NW - 1) / (2 * NW));  // even owned span (<=94)
  const int Se = (S + 1) & ~1;
  const int o0 = min(wv * oS, Se);  // even
  const int o1 = min(o0 + oS, S);
  const int p0 = max(0, o0 - 26);   // even ghost bottom (26 >= 2*12+2)
  const int s0 = p0 + 2 * lane;     // blank state (even)
  const int s1 = s0 + 1;            // label state (odd)

  int e1 = 0;
  bool skip = false;
  if (s1 < S) {
    int li = s1 >> 1;
    e1 = lab[li];
    if (s1 >= 3) skip = (e1 != 0) && (e1 != lab[li - 1]);
  }

  float a0 = NEGF, a1 = NEGF;
  if (wv == 0 && lane == 0) {
    a0 = act_b[0] * L2E;
    a1 = act_b[e1] * L2E;  // S >= 3 always (len >= 1)
  }

  float gL0, gL1, gL2, gL3, gL4, gL5;  // label logits (divergent gather)
  float gB0, gB1, gB2, gB3, gB4, gB5;  // blank logits (wave-uniform)

#define PREF(GL, GB, ROW)                                  \
  {                                                        \
    const float* rp_ = act_b + (size_t)(ROW) * (BB * VV);  \
    GB = rp_[0];                                           \
    GL = rp_[e1];                                          \
  }

#define STEPK(GL, GB)                                                     \
  {                                                                       \
    float pe = shr1_negf(a1);                                             \
    /* u = lse2(a0, pe): blank state's sum */                             \
    float m0 = fmaxf(a0, pe);                                             \
    float d0 = fminf(a0, pe) - m0;                                        \
    float u = m0 + __builtin_log2f(1.0f + __builtin_exp2f(d0));           \
    /* v = lse2(a1, w), w = skip ? u : a0  (== lse3(a1,a0,pe) if skip) */ \
    float w = skip ? u : a0;                                              \
    float m1 = fmaxf(a1, w);                                              \
    float d1 = fminf(a1, w) - m1;                                         \
    float v = m1 + __builtin_log2f(1.0f + __builtin_exp2f(d1));           \
    a0 = __builtin_fmaf(GB, L2E, u);                                      \
    a1 = __builtin_fmaf(GL, L2E, v);                                      \
  }

  // raw-barrier refresh: lgkmcnt-only fences; prefetch (vmcnt) stays in flight
#define REFRESH()                                        \
  {                                                      \
    asm volatile("s_waitcnt lgkmcnt(0)" ::: "memory");   \
    __builtin_amdgcn_s_barrier();                        \
    if (s0 >= o0 && s0 < o1) xall[s0] = a0;              \
    if (s1 >= o0 && s1 < o1) xall[s1] = a1;              \
    asm volatile("s_waitcnt lgkmcnt(0)" ::: "memory");   \
    __builtin_amdgcn_s_barrier();                        \
    if (s0 < o0) {                                       \
      a0 = xall[s0];                                     \
      a1 = (s1 < S) ? xall[s1] : NEGF;                   \
    }                                                    \
  }

  // window step: consume slot, refill same slot with row t+OFF+6 (no branches)
#define W1(OFF, GL, GB)                    \
  STEPK(GL, GB);                           \
  PREF(GL, GB, min(t + (OFF) + 6, Tlm1));

  // tail step: same rotation, with exit checks
#define T1(GL, GB)                         \
  STEPK(GL, GB);                           \
  PREF(GL, GB, min(t + 6, Tlm1));          \
  ++t;                                     \
  if (t >= Tl) break;

  // prologue: slots 0..5 = rows 1..6 (clamped)
  PREF(gL0, gB0, min(1, Tlm1));
  PREF(gL1, gB1, min(2, Tlm1));
  PREF(gL2, gB2, min(3, Tlm1));
  PREF(gL3, gB3, min(4, Tlm1));
  PREF(gL4, gB4, min(5, Tlm1));
  PREF(gL5, gB5, min(6, Tlm1));

  int t = 1;
  // main: branch-free 12-step windows; raw-barrier refresh each window
  while (t + 12 <= Tl) {
    W1(0, gL0, gB0)
    W1(1, gL1, gB1)
    W1(2, gL2, gB2)
    W1(3, gL3, gB3)
    W1(4, gL4, gB4)
    W1(5, gL5, gB5)
    W1(6, gL0, gB0)
    W1(7, gL1, gB1)
    W1(8, gL2, gB2)
    W1(9, gL3, gB3)
    W1(10, gL4, gB4)
    W1(11, gL5, gB5)
    t += 12;
    REFRESH();
  }
  // tail: <= 11 steps (ghost covers 13), slot alignment preserved
  while (t < Tl) {
    T1(gL0, gB0)
    T1(gL1, gB1)
    T1(gL2, gB2)
    T1(gL3, gB3)
    T1(gL4, gB4)
    T1(gL5, gB5)
  }
#undef T1
#undef W1
#undef REFRESH
#undef STEPK
#undef PREF

  // end = logaddexp(al[2*len], al[2*len-1]) from owned states
  __syncthreads();
  if (s0 >= o0 && s0 < o1 && s0 == 2 * len) fin[0] = a0;
  if (s1 >= o0 && s1 < o1 && s1 == 2 * len - 1) fin[1] = a1;
  __syncthreads();
  if (tid == 0) {
    float a = fin[0], c = fin[1];
    float m = fmaxf(a, c);
    float e = m + __builtin_log2f(__builtin_exp2f(a - m) + __builtin_exp2f(c - m));
    ends[hyp * BB + b] = e;
  }
}

// ---------------------------------------------------------------------------
// Kernel 3: out[b] = (end_hyp' - end_gt') * ln2 + 1.0  (log2-domain ends)
// ---------------------------------------------------------------------------
__global__ void final_kernel(const float* __restrict__ ends,
                             float* __restrict__ out) {
  int b = threadIdx.x;
  if (b < BB) out[b] = (ends[BB + b] - ends[b]) * LN2F + 1.0f;
}

extern "C" void kernel_launch(void* const* d_in, const int* in_sizes, int n_in,
                              void* d_out, int out_size, void* d_ws,
                              size_t ws_size, hipStream_t stream) {
  const float* acts = (const float*)d_in[0];
  const int* labels = (const int*)d_in[1];
  const int* act_lens = (const int*)d_in[2];
  const int* label_lens = (const int*)d_in[3];
  float* out = (float*)d_out;

  char* ws = (char*)d_ws;
  int* dec = (int*)ws;                                          // B*LCAP ints
  int* dec_lens = (int*)(ws + (size_t)BB * LCAP * 4);           // B ints
  float* ends = (float*)(ws + (size_t)BB * LCAP * 4 + BB * 4);  // 2*B floats

  decode_kernel<<<dim3(BB), dim3(256), 0, stream>>>(acts, act_lens, dec, dec_lens);
  // 84KB dynamic LDS: forces 1 block/CU so the 192 blocks spread over 192
  // CUs -> max 11 waves / 4 SIMDs per CU (2.75 waves/SIMD).
  ctc_kernel<<<dim3(2 * BB), dim3(64 * NW), 84 * 1024, stream>>>(
      acts, labels, act_lens, label_lens, dec, dec_lens, ends);
  final_kernel<<<dim3(1), dim3(128), 0, stream>>>(ends, out);
}

// Round 19
// 356.756 us; speedup vs baseline: 4.5661x; 1.1068x over previous
//
#include <hip/hip_runtime.h>

#define TT 1500
#define BB 96
#define VV 128
#define LGT 256
#define LCAP 512
#define NEGF (-1.0e30f)
#define L2E 1.4426950408889634f
#define LN2F 0.6931471805599453f
#define NW 11  // waves per CTC block (704 threads)

// ---------------------------------------------------------------------------
// Kernel 1: greedy decode (unchanged).
// ---------------------------------------------------------------------------
__global__ __launch_bounds__(256) void decode_kernel(
    const float* __restrict__ acts, const int* __restrict__ act_lens,
    int* __restrict__ dec, int* __restrict__ dec_lens) {
  __shared__ int preds[TT];
  __shared__ int sc[256];
  const int b = blockIdx.x;
  const int tid = threadIdx.x;
  const int Tl = act_lens[b];
  for (int t = tid; t < Tl; t += 256) {
    const float4* r4 = (const float4*)(acts + ((size_t)t * BB + b) * VV);
    float best = -3.4e38f;
    int bi = 0;
#pragma unroll
    for (int i = 0; i < VV / 4; i++) {
      float4 v = r4[i];
      if (v.x > best) { best = v.x; bi = 4 * i; }
      if (v.y > best) { best = v.y; bi = 4 * i + 1; }
      if (v.z > best) { best = v.z; bi = 4 * i + 2; }
      if (v.w > best) { best = v.w; bi = 4 * i + 3; }
    }
    preds[t] = bi;
  }
  __syncthreads();

  int pv[6];
  bool fl[6];
  int cnt = 0;
#pragma unroll
  for (int j = 0; j < 6; j++) {
    int t = tid * 6 + j;
    bool valid = t < Tl;
    int p = valid ? preds[t] : 0;
    int pr = (t == 0) ? -1 : (valid ? preds[t - 1] : -1);
    bool f = valid && (p != 0) && (p != pr);
    pv[j] = p;
    fl[j] = f;
    cnt += f;
  }
  sc[tid] = cnt;
  __syncthreads();
  for (int off = 1; off < 256; off <<= 1) {
    int v = sc[tid];
    if (tid >= off) v += sc[tid - off];
    __syncthreads();
    sc[tid] = v;
    __syncthreads();
  }
  int pos = sc[tid] - cnt;  // exclusive prefix
  int total = sc[255];
  int* db = dec + (size_t)b * LCAP;
#pragma unroll
  for (int j = 0; j < 6; j++) {
    if (fl[j]) {
      if (pos < LCAP) db[pos] = pv[j];
      pos++;
    }
  }
  if (tid == 0) {
    if (total == 0) db[0] = 0;
    dec_lens[b] = max(1, min(total, LCAP));
  }
}

// ---------------------------------------------------------------------------
// Kernel 2: CTC, r18 structure exactly (373us, absmax 0.0). SINGLE CHANGE:
// the two log2(1+2^d) tails use HW exp2 + POLYNOMIAL log1p instead of HW
// log2: with x = 2^d in [0,1], log2(1+x) = (ln3 + ln(1+w))*L2E - 1 where
// w = (2x-1)/3, |w| <= 1/3; ln(1+w) by 6-term alternating series
// (|err| <= (1/3)^7/7 = 6.5e-5). Trans ops/step: 4 -> 2.
// ---------------------------------------------------------------------------
__device__ __forceinline__ float shr1_negf(float x) {
  // lane i <- lane i-1's x; lane 0 <- NEGF.  DPP ctrl 0x138 = wave_shr:1.
  int r = __builtin_amdgcn_update_dpp(__float_as_int(NEGF), __float_as_int(x),
                                      0x138, 0xf, 0xf, false);
  return __int_as_float(r);
}

// log2(1+x) for x in [0,1]; poly only (no trans). abs err < 1e-4.
__device__ __forceinline__ float log1p2f(float x) {
  float w = __builtin_fmaf(x, 0.6666666666666666f, -0.3333333333333333f);
  float p = -0.16666666666666666f;               // -1/6
  p = __builtin_fmaf(p, w, 0.2f);                // +1/5
  p = __builtin_fmaf(p, w, -0.25f);              // -1/4
  p = __builtin_fmaf(p, w, 0.3333333333333333f); // +1/3
  p = __builtin_fmaf(p, w, -0.5f);               // -1/2
  p = __builtin_fmaf(p, w, 1.0f);                // +1
  // log2(1+x) = (p*w)*L2E + (log2(3) - 1)
  return __builtin_fmaf(p * w, L2E, 0.5849625007211562f);
}

__global__ __launch_bounds__(64 * NW, 1) void ctc_kernel(
    const float* __restrict__ acts, const int* __restrict__ labels_gt,
    const int* __restrict__ act_lens, const int* __restrict__ label_lens,
    const int* __restrict__ dec, const int* __restrict__ dec_lens,
    float* __restrict__ ends) {
  __shared__ float xall[2 * LCAP + 2];
  __shared__ float fin[2];
  const int b = blockIdx.x >> 1;
  const int hyp = blockIdx.x & 1;
  const int Tl = act_lens[b];
  const int len = hyp ? dec_lens[b] : label_lens[b];
  const int* lab = hyp ? (dec + (size_t)b * LCAP) : (labels_gt + (size_t)b * LGT);
  const int S = 2 * len + 1;
  const float* act_b = acts + (size_t)b * VV;  // acts[(t*BB + b)*VV + v]
  const int Tlm1 = Tl - 1;

  const int tid = threadIdx.x;
  const int lane = tid & 63, wv = tid >> 6;
  const int oS = 2 * ((S + 2 * NW - 1) / (2 * NW));  // even owned span (<=94)
  const int Se = (S + 1) & ~1;
  const int o0 = min(wv * oS, Se);  // even
  const int o1 = min(o0 + oS, S);
  const int p0 = max(0, o0 - 26);   // even ghost bottom (26 >= 2*12+2)
  const int s0 = p0 + 2 * lane;     // blank state (even)
  const int s1 = s0 + 1;            // label state (odd)

  int e1 = 0;
  bool skip = false;
  if (s1 < S) {
    int li = s1 >> 1;
    e1 = lab[li];
    if (s1 >= 3) skip = (e1 != 0) && (e1 != lab[li - 1]);
  }

  float a0 = NEGF, a1 = NEGF;
  if (wv == 0 && lane == 0) {
    a0 = act_b[0] * L2E;
    a1 = act_b[e1] * L2E;  // S >= 3 always (len >= 1)
  }

  float gL0, gL1, gL2, gL3, gL4, gL5;  // label logits (divergent gather)
  float gB0, gB1, gB2, gB3, gB4, gB5;  // blank logits (wave-uniform)

#define PREF(GL, GB, ROW)                                  \
  {                                                        \
    const float* rp_ = act_b + (size_t)(ROW) * (BB * VV);  \
    GB = rp_[0];                                           \
    GL = rp_[e1];                                          \
  }

#define STEPK(GL, GB)                                                     \
  {                                                                       \
    float pe = shr1_negf(a1);                                             \
    /* u = lse2(a0, pe) via exp2 + poly log1p */                          \
    float m0 = fmaxf(a0, pe);                                             \
    float d0 = fminf(a0, pe) - m0;                                        \
    float u = m0 + log1p2f(__builtin_exp2f(d0));                          \
    /* v = lse2(a1, w), w = skip ? u : a0 */                              \
    float w = skip ? u : a0;                                              \
    float m1 = fmaxf(a1, w);                                              \
    float d1 = fminf(a1, w) - m1;                                         \
    float v = m1 + log1p2f(__builtin_exp2f(d1));                          \
    a0 = __builtin_fmaf(GB, L2E, u);                                      \
    a1 = __builtin_fmaf(GL, L2E, v);                                      \
  }

  // raw-barrier refresh: lgkmcnt-only fences; prefetch (vmcnt) stays in flight
#define REFRESH()                                        \
  {                                                      \
    asm volatile("s_waitcnt lgkmcnt(0)" ::: "memory");   \
    __builtin_amdgcn_s_barrier();                        \
    if (s0 >= o0 && s0 < o1) xall[s0] = a0;              \
    if (s1 >= o0 && s1 < o1) xall[s1] = a1;              \
    asm volatile("s_waitcnt lgkmcnt(0)" ::: "memory");   \
    __builtin_amdgcn_s_barrier();                        \
    if (s0 < o0) {                                       \
      a0 = xall[s0];                                     \
      a1 = (s1 < S) ? xall[s1] : NEGF;                   \
    }                                                    \
  }

  // window step: consume slot, refill same slot with row t+OFF+6 (no branches)
#define W1(OFF, GL, GB)                    \
  STEPK(GL, GB);                           \
  PREF(GL, GB, min(t + (OFF) + 6, Tlm1));

  // tail step: same rotation, with exit checks
#define T1(GL, GB)                         \
  STEPK(GL, GB);                           \
  PREF(GL, GB, min(t + 6, Tlm1));          \
  ++t;                                     \
  if (t >= Tl) break;

  // prologue: slots 0..5 = rows 1..6 (clamped)
  PREF(gL0, gB0, min(1, Tlm1));
  PREF(gL1, gB1, min(2, Tlm1));
  PREF(gL2, gB2, min(3, Tlm1));
  PREF(gL3, gB3, min(4, Tlm1));
  PREF(gL4, gB4, min(5, Tlm1));
  PREF(gL5, gB5, min(6, Tlm1));

  int t = 1;
  // main: branch-free 12-step windows; raw-barrier refresh each window
  while (t + 12 <= Tl) {
    W1(0, gL0, gB0)
    W1(1, gL1, gB1)
    W1(2, gL2, gB2)
    W1(3, gL3, gB3)
    W1(4, gL4, gB4)
    W1(5, gL5, gB5)
    W1(6, gL0, gB0)
    W1(7, gL1, gB1)
    W1(8, gL2, gB2)
    W1(9, gL3, gB3)
    W1(10, gL4, gB4)
    W1(11, gL5, gB5)
    t += 12;
    REFRESH();
  }
  // tail: <= 11 steps (ghost covers 13), slot alignment preserved
  while (t < Tl) {
    T1(gL0, gB0)
    T1(gL1, gB1)
    T1(gL2, gB2)
    T1(gL3, gB3)
    T1(gL4, gB4)
    T1(gL5, gB5)
  }
#undef T1
#undef W1
#undef REFRESH
#undef STEPK
#undef PREF

  // end = logaddexp(al[2*len], al[2*len-1]) from owned states
  __syncthreads();
  if (s0 >= o0 && s0 < o1 && s0 == 2 * len) fin[0] = a0;
  if (s1 >= o0 && s1 < o1 && s1 == 2 * len - 1) fin[1] = a1;
  __syncthreads();
  if (tid == 0) {
    float a = fin[0], c = fin[1];
    float m = fmaxf(a, c);
    float e = m + __builtin_log2f(__builtin_exp2f(a - m) + __builtin_exp2f(c - m));
    ends[hyp * BB + b] = e;
  }
}

// ---------------------------------------------------------------------------
// Kernel 3: out[b] = (end_hyp' - end_gt') * ln2 + 1.0  (log2-domain ends)
// ---------------------------------------------------------------------------
__global__ void final_kernel(const float* __restrict__ ends,
                             float* __restrict__ out) {
  int b = threadIdx.x;
  if (b < BB) out[b] = (ends[BB + b] - ends[b]) * LN2F + 1.0f;
}

extern "C" void kernel_launch(void* const* d_in, const int* in_sizes, int n_in,
                              void* d_out, int out_size, void* d_ws,
                              size_t ws_size, hipStream_t stream) {
  const float* acts = (const float*)d_in[0];
  const int* labels = (const int*)d_in[1];
  const int* act_lens = (const int*)d_in[2];
  const int* label_lens = (const int*)d_in[3];
  float* out = (float*)d_out;

  char* ws = (char*)d_ws;
  int* dec = (int*)ws;                                          // B*LCAP ints
  int* dec_lens = (int*)(ws + (size_t)BB * LCAP * 4);           // B ints
  float* ends = (float*)(ws + (size_t)BB * LCAP * 4 + BB * 4);  // 2*B floats

  decode_kernel<<<dim3(BB), dim3(256), 0, stream>>>(acts, act_lens, dec, dec_lens);
  // 84KB dynamic LDS: forces 1 block/CU so the 192 blocks spread over 192
  // CUs -> max 11 waves / 4 SIMDs per CU (2.75 waves/SIMD).
  ctc_kernel<<<dim3(2 * BB), dim3(64 * NW), 84 * 1024, stream>>>(
      acts, labels, act_lens, label_lens, dec, dec_lens, ends);
  final_kernel<<<dim3(1), dim3(128), 0, stream>>>(ends, out);
}

// Round 20
// 347.982 us; speedup vs baseline: 4.6812x; 1.0252x over previous
//
#include <hip/hip_runtime.h>

#define TT 1500
#define BB 96
#define VV 128
#define LGT 256
#define LCAP 512
#define NEGF (-1.0e30f)
#define L2E 1.4426950408889634f
#define LN2F 0.6931471805599453f
#define NW 11  // waves per CTC block (704 threads)
#define GH 34  // ghost states: 2*HREF=32 < 34; oS(<=94)+34 <= 128
#define HREF 16

// ---------------------------------------------------------------------------
// Kernel 1: greedy decode (unchanged).
// ---------------------------------------------------------------------------
__global__ __launch_bounds__(256) void decode_kernel(
    const float* __restrict__ acts, const int* __restrict__ act_lens,
    int* __restrict__ dec, int* __restrict__ dec_lens) {
  __shared__ int preds[TT];
  __shared__ int sc[256];
  const int b = blockIdx.x;
  const int tid = threadIdx.x;
  const int Tl = act_lens[b];
  for (int t = tid; t < Tl; t += 256) {
    const float4* r4 = (const float4*)(acts + ((size_t)t * BB + b) * VV);
    float best = -3.4e38f;
    int bi = 0;
#pragma unroll
    for (int i = 0; i < VV / 4; i++) {
      float4 v = r4[i];
      if (v.x > best) { best = v.x; bi = 4 * i; }
      if (v.y > best) { best = v.y; bi = 4 * i + 1; }
      if (v.z > best) { best = v.z; bi = 4 * i + 2; }
      if (v.w > best) { best = v.w; bi = 4 * i + 3; }
    }
    preds[t] = bi;
  }
  __syncthreads();

  int pv[6];
  bool fl[6];
  int cnt = 0;
#pragma unroll
  for (int j = 0; j < 6; j++) {
    int t = tid * 6 + j;
    bool valid = t < Tl;
    int p = valid ? preds[t] : 0;
    int pr = (t == 0) ? -1 : (valid ? preds[t - 1] : -1);
    bool f = valid && (p != 0) && (p != pr);
    pv[j] = p;
    fl[j] = f;
    cnt += f;
  }
  sc[tid] = cnt;
  __syncthreads();
  for (int off = 1; off < 256; off <<= 1) {
    int v = sc[tid];
    if (tid >= off) v += sc[tid - off];
    __syncthreads();
    sc[tid] = v;
    __syncthreads();
  }
  int pos = sc[tid] - cnt;  // exclusive prefix
  int total = sc[255];
  int* db = dec + (size_t)b * LCAP;
#pragma unroll
  for (int j = 0; j < 6; j++) {
    if (fl[j]) {
      if (pos < LCAP) db[pos] = pv[j];
      pos++;
    }
  }
  if (tid == 0) {
    if (total == 0) db[0] = 0;
    dec_lens[b] = max(1, min(total, LCAP));
  }
}

// ---------------------------------------------------------------------------
// Kernel 2: CTC, r19 math exactly (335us, absmax 0.0). CHANGES (refresh cost
// only; exchanged values identical): (1) HREF 12->16 with ghost 26->34 and an
// 8-slot prefetch ring (16 steps = 2 rotations, 8-step load lead);
// (2) ONE raw s_barrier per window via parity double-buffered exchange LDS
// (write buf[k&1] -> lgkmcnt(0) -> barrier -> read buf[k&1]; next window
// uses the other buffer; 2-window reuse is fenced by the interleaved
// barrier). Barrier+drain events: 250 -> 94 per 1500 steps.
// ---------------------------------------------------------------------------
__device__ __forceinline__ float shr1_negf(float x) {
  // lane i <- lane i-1's x; lane 0 <- NEGF.  DPP ctrl 0x138 = wave_shr:1.
  int r = __builtin_amdgcn_update_dpp(__float_as_int(NEGF), __float_as_int(x),
                                      0x138, 0xf, 0xf, false);
  return __int_as_float(r);
}

// log2(1+x) for x in [0,1]; poly only (no trans). abs err < 1e-4.
__device__ __forceinline__ float log1p2f(float x) {
  float w = __builtin_fmaf(x, 0.6666666666666666f, -0.3333333333333333f);
  float p = -0.16666666666666666f;               // -1/6
  p = __builtin_fmaf(p, w, 0.2f);                // +1/5
  p = __builtin_fmaf(p, w, -0.25f);              // -1/4
  p = __builtin_fmaf(p, w, 0.3333333333333333f); // +1/3
  p = __builtin_fmaf(p, w, -0.5f);               // -1/2
  p = __builtin_fmaf(p, w, 1.0f);                // +1
  return __builtin_fmaf(p * w, L2E, 0.5849625007211562f);  // + log2(3)-1
}

__global__ __launch_bounds__(64 * NW, 1) void ctc_kernel(
    const float* __restrict__ acts, const int* __restrict__ labels_gt,
    const int* __restrict__ act_lens, const int* __restrict__ label_lens,
    const int* __restrict__ dec, const int* __restrict__ dec_lens,
    float* __restrict__ ends) {
  __shared__ float xall[2][2 * LCAP + 2];  // parity double buffer
  __shared__ float fin[2];
  const int b = blockIdx.x >> 1;
  const int hyp = blockIdx.x & 1;
  const int Tl = act_lens[b];
  const int len = hyp ? dec_lens[b] : label_lens[b];
  const int* lab = hyp ? (dec + (size_t)b * LCAP) : (labels_gt + (size_t)b * LGT);
  const int S = 2 * len + 1;
  const float* act_b = acts + (size_t)b * VV;  // acts[(t*BB + b)*VV + v]
  const int Tlm1 = Tl - 1;

  const int tid = threadIdx.x;
  const int lane = tid & 63, wv = tid >> 6;
  const int oS = 2 * ((S + 2 * NW - 1) / (2 * NW));  // even owned span (<=94)
  const int Se = (S + 1) & ~1;
  const int o0 = min(wv * oS, Se);  // even
  const int o1 = min(o0 + oS, S);
  const int p0 = max(0, o0 - GH);   // even ghost bottom
  const int s0 = p0 + 2 * lane;     // blank state (even)
  const int s1 = s0 + 1;            // label state (odd)

  int e1 = 0;
  bool skip = false;
  if (s1 < S) {
    int li = s1 >> 1;
    e1 = lab[li];
    if (s1 >= 3) skip = (e1 != 0) && (e1 != lab[li - 1]);
  }

  float a0 = NEGF, a1 = NEGF;
  if (wv == 0 && lane == 0) {
    a0 = act_b[0] * L2E;
    a1 = act_b[e1] * L2E;  // S >= 3 always (len >= 1)
  }

  float gL0, gL1, gL2, gL3, gL4, gL5, gL6, gL7;  // label logits (gather)
  float gB0, gB1, gB2, gB3, gB4, gB5, gB6, gB7;  // blank logits (uniform)

#define PREF(GL, GB, ROW)                                  \
  {                                                        \
    const float* rp_ = act_b + (size_t)(ROW) * (BB * VV);  \
    GB = rp_[0];                                           \
    GL = rp_[e1];                                          \
  }

#define STEPK(GL, GB)                                                     \
  {                                                                       \
    float pe = shr1_negf(a1);                                             \
    /* u = lse2(a0, pe) via exp2 + poly log1p */                          \
    float m0 = fmaxf(a0, pe);                                             \
    float d0 = fminf(a0, pe) - m0;                                        \
    float u = m0 + log1p2f(__builtin_exp2f(d0));                          \
    /* v = lse2(a1, w), w = skip ? u : a0 */                              \
    float w = skip ? u : a0;                                              \
    float m1 = fmaxf(a1, w);                                              \
    float d1 = fminf(a1, w) - m1;                                         \
    float v = m1 + log1p2f(__builtin_exp2f(d1));                          \
    a0 = __builtin_fmaf(GB, L2E, u);                                      \
    a1 = __builtin_fmaf(GL, L2E, v);                                      \
  }

  // ONE-barrier refresh with parity buffer (vmcnt prefetch stays in flight)
#define REFRESH(K)                                       \
  {                                                      \
    float* xs = xall[(K)&1];                             \
    if (s0 >= o0 && s0 < o1) xs[s0] = a0;                \
    if (s1 >= o0 && s1 < o1) xs[s1] = a1;                \
    asm volatile("s_waitcnt lgkmcnt(0)" ::: "memory");   \
    __builtin_amdgcn_s_barrier();                        \
    if (s0 < o0) {                                       \
      a0 = xs[s0];                                       \
      a1 = (s1 < S) ? xs[s1] : NEGF;                     \
    }                                                    \
  }

  // window step: consume slot, refill same slot with row t+OFF+8
#define W1(OFF, GL, GB)                    \
  STEPK(GL, GB);                           \
  PREF(GL, GB, min(t + (OFF) + 8, Tlm1));

  // tail step: same rotation, with exit checks
#define T1(GL, GB)                         \
  STEPK(GL, GB);                           \
  PREF(GL, GB, min(t + 8, Tlm1));          \
  ++t;                                     \
  if (t >= Tl) break;

  // prologue: slots 0..7 = rows 1..8 (clamped)
  PREF(gL0, gB0, min(1, Tlm1));
  PREF(gL1, gB1, min(2, Tlm1));
  PREF(gL2, gB2, min(3, Tlm1));
  PREF(gL3, gB3, min(4, Tlm1));
  PREF(gL4, gB4, min(5, Tlm1));
  PREF(gL5, gB5, min(6, Tlm1));
  PREF(gL6, gB6, min(7, Tlm1));
  PREF(gL7, gB7, min(8, Tlm1));

  int t = 1, k = 0;
  // main: branch-free 16-step windows; one-barrier refresh per window
  while (t + HREF <= Tl) {
    W1(0, gL0, gB0)
    W1(1, gL1, gB1)
    W1(2, gL2, gB2)
    W1(3, gL3, gB3)
    W1(4, gL4, gB4)
    W1(5, gL5, gB5)
    W1(6, gL6, gB6)
    W1(7, gL7, gB7)
    W1(8, gL0, gB0)
    W1(9, gL1, gB1)
    W1(10, gL2, gB2)
    W1(11, gL3, gB3)
    W1(12, gL4, gB4)
    W1(13, gL5, gB5)
    W1(14, gL6, gB6)
    W1(15, gL7, gB7)
    t += HREF;
    ++k;
    REFRESH(k);
  }
  // tail: <= 15 steps (ghost covers 2*15=30 < 34), slots aligned (16%8==0)
  while (t < Tl) {
    T1(gL0, gB0)
    T1(gL1, gB1)
    T1(gL2, gB2)
    T1(gL3, gB3)
    T1(gL4, gB4)
    T1(gL5, gB5)
    T1(gL6, gB6)
    T1(gL7, gB7)
  }
#undef T1
#undef W1
#undef REFRESH
#undef STEPK
#undef PREF

  // end = logaddexp(al[2*len], al[2*len-1]) from owned states
  __syncthreads();
  if (s0 >= o0 && s0 < o1 && s0 == 2 * len) fin[0] = a0;
  if (s1 >= o0 && s1 < o1 && s1 == 2 * len - 1) fin[1] = a1;
  __syncthreads();
  if (tid == 0) {
    float a = fin[0], c = fin[1];
    float m = fmaxf(a, c);
    float e = m + __builtin_log2f(__builtin_exp2f(a - m) + __builtin_exp2f(c - m));
    ends[hyp * BB + b] = e;
  }
}

// ---------------------------------------------------------------------------
// Kernel 3: out[b] = (end_hyp' - end_gt') * ln2 + 1.0  (log2-domain ends)
// ---------------------------------------------------------------------------
__global__ void final_kernel(const float* __restrict__ ends,
                             float* __restrict__ out) {
  int b = threadIdx.x;
  if (b < BB) out[b] = (ends[BB + b] - ends[b]) * LN2F + 1.0f;
}

extern "C" void kernel_launch(void* const* d_in, const int* in_sizes, int n_in,
                              void* d_out, int out_size, void* d_ws,
                              size_t ws_size, hipStream_t stream) {
  const float* acts = (const float*)d_in[0];
  const int* labels = (const int*)d_in[1];
  const int* act_lens = (const int*)d_in[2];
  const int* label_lens = (const int*)d_in[3];
  float* out = (float*)d_out;

  char* ws = (char*)d_ws;
  int* dec = (int*)ws;                                          // B*LCAP ints
  int* dec_lens = (int*)(ws + (size_t)BB * LCAP * 4);           // B ints
  float* ends = (float*)(ws + (size_t)BB * LCAP * 4 + BB * 4);  // 2*B floats

  decode_kernel<<<dim3(BB), dim3(256), 0, stream>>>(acts, act_lens, dec, dec_lens);
  // 80KB dynamic LDS (+8.2KB static): forces 1 block/CU so 192 blocks spread
  // over 192 CUs -> 11 waves / 4 SIMDs = 2.75 waves/SIMD.
  ctc_kernel<<<dim3(2 * BB), dim3(64 * NW), 80 * 1024, stream>>>(
      acts, labels, act_lens, label_lens, dec, dec_lens, ends);
  final_kernel<<<dim3(1), dim3(128), 0, stream>>>(ends, out);
}